// Round 1
// baseline (1624.609 us; speedup 1.0000x reference)
//
#include <hip/hip_runtime.h>
#include <cstdint>

#define BB 4
#define NN 20000
#define CC 512
#define MM 1024
#define GTHR 0.1f
#define FPS_T 512
#define QB 8

#define INFF __builtin_huge_valf()

// ---------------------------------------------------------------------------
// Stage 1: mask + order-preserving compaction (one block per batch)
// ---------------------------------------------------------------------------
__global__ void compact_kernel(const float* __restrict__ pc,
                               const float* __restrict__ obj,
                               const float* __restrict__ grasp,
                               float4* __restrict__ cxyz,
                               int* __restrict__ cidx,
                               int* __restrict__ nv) {
  int b = blockIdx.x;
  int t = threadIdx.x;
  __shared__ int wtot[2][4];
  int runbase = 0;
  const float* pcb = pc + (size_t)b * NN * 3;
  const float* o0 = obj + (size_t)b * 2 * NN;
  const float* o1 = o0 + NN;
  const float* gb = grasp + (size_t)b * NN;
  float4* cxyzb = cxyz + (size_t)b * NN;
  int* cidxb = cidx + (size_t)b * NN;
  const int nchunk = (NN + 255) / 256;
  for (int c = 0; c < nchunk; ++c) {
    int i = c * 256 + t;
    bool valid = false;
    float x = 0.f, y = 0.f, z = 0.f;
    if (i < NN) {
      float a0 = o0[i], a1 = o1[i], g = gb[i];
      // argmax(axis=1)==1  <=>  o1 > o0 strictly (argmax picks first max)
      valid = (a1 > a0) && (g > GTHR);
      if (valid) { x = pcb[3 * i]; y = pcb[3 * i + 1]; z = pcb[3 * i + 2]; }
    }
    unsigned long long bal = __ballot(valid);
    int lane = t & 63, w = t >> 6;
    int pre = __popcll(bal & ((1ull << lane) - 1ull));
    if (lane == 0) wtot[c & 1][w] = (int)__popcll(bal);
    __syncthreads();
    int woff = 0, ctot = 0;
#pragma unroll
    for (int k = 0; k < 4; ++k) {
      int v = wtot[c & 1][k];
      if (k < w) woff += v;
      ctot += v;
    }
    if (valid) {
      int pos = runbase + woff + pre;
      cidxb[pos] = i;
      cxyzb[pos] = make_float4(x, y, z, 0.f);
    }
    runbase += ctot;
    // double-buffered wtot: next chunk writes the other buffer; the barrier
    // inside the next chunk orders re-use of this one.
  }
  if (t == 0) nv[b] = runbase;
}

// ---------------------------------------------------------------------------
// Stage 2: FPS over compacted points (one block per batch)
// ---------------------------------------------------------------------------
__device__ __forceinline__ bool argmax_win(float va, int ja, float vb, int jb) {
  // (va,ja) beats (vb,jb) for argmax with first-occurrence tie-break
  return (va > vb) || (va == vb && ja < jb);
}

__device__ __forceinline__ void block_argmax(float bestv, int bestj,
                                             float* pv, int* pj, int buf,
                                             int lane, int w,
                                             float& vwin, int& jwin) {
#pragma unroll
  for (int off = 32; off; off >>= 1) {
    float ov = __shfl_xor(bestv, off);
    int oj = __shfl_xor(bestj, off);
    if (argmax_win(ov, oj, bestv, bestj)) { bestv = ov; bestj = oj; }
  }
  if (lane == 0) { pv[buf * 8 + w] = bestv; pj[buf * 8 + w] = bestj; }
  __syncthreads();
  vwin = pv[buf * 8]; jwin = pj[buf * 8];
#pragma unroll
  for (int k = 1; k < 8; ++k) {
    float vk = pv[buf * 8 + k]; int jk = pj[buf * 8 + k];
    if (argmax_win(vk, jk, vwin, jwin)) { vwin = vk; jwin = jk; }
  }
}

template <int K>
__device__ void fps_main(int nv_, const float4* __restrict__ cxyzb,
                         const int* __restrict__ cidxb,
                         int* __restrict__ fpsIdxb,
                         float4* __restrict__ fpsXyzb,
                         float* pv, int* pj) {
  const int t = threadIdx.x;
  const int lane = t & 63, w = t >> 6;
  float x[K], y[K], z[K], mind[K];
#pragma unroll
  for (int s = 0; s < K; ++s) {
    int j = s * FPS_T + t;
    if (j < nv_) {
      float4 p = cxyzb[j];
      x[s] = p.x; y[s] = p.y; z[s] = p.z; mind[s] = INFF;
    } else {
      x[s] = 0.f; y[s] = 0.f; z[s] = 0.f; mind[s] = -INFF;  // never selected
    }
  }
  float4 q = cxyzb[0];  // first = first masked point = compacted idx 0
  if (t == 0) { fpsIdxb[0] = cidxb[0]; fpsXyzb[0] = q; }
  int buf = 0;
  for (int r = 1; r < MM; ++r) {
    float bestv = -INFF; int bestj = 0x7fffffff;
#pragma unroll
    for (int s = 0; s < K; ++s) {
      float dx = x[s] - q.x, dy = y[s] - q.y, dz = z[s] - q.z;
      float d = fmaf(dz, dz, fmaf(dy, dy, dx * dx));
      float m = fminf(mind[s], d);
      mind[s] = m;
      if (m > bestv) { bestv = m; bestj = s * FPS_T + t; }  // strict >: lowest j on ties
    }
    float vwin; int jwin;
    block_argmax(bestv, bestj, pv, pj, buf, lane, w, vwin, jwin);
    q = cxyzb[jwin];  // uniform broadcast load (L1/L2)
    if (t == 0) { fpsIdxb[r] = cidxb[jwin]; fpsXyzb[r] = q; }
    buf ^= 1;
  }
}

// correct-but-slow path for nv > 12*FPS_T (never triggered by bench data)
__device__ void fps_fallback(int nv_, const float4* __restrict__ cxyzb,
                             const int* __restrict__ cidxb,
                             int* __restrict__ fpsIdxb,
                             float4* __restrict__ fpsXyzb,
                             float* __restrict__ mindg, float* pv, int* pj) {
  const int t = threadIdx.x;
  const int lane = t & 63, w = t >> 6;
  for (int j = t; j < nv_; j += FPS_T) mindg[j] = INFF;
  __syncthreads();
  float4 q = cxyzb[0];
  if (t == 0) { fpsIdxb[0] = cidxb[0]; fpsXyzb[0] = q; }
  int buf = 0;
  for (int r = 1; r < MM; ++r) {
    float bestv = -INFF; int bestj = 0x7fffffff;
    for (int j = t; j < nv_; j += FPS_T) {
      float4 p = cxyzb[j];
      float dx = p.x - q.x, dy = p.y - q.y, dz = p.z - q.z;
      float d = fmaf(dz, dz, fmaf(dy, dy, dx * dx));
      float m = fminf(mindg[j], d);
      mindg[j] = m;
      if (m > bestv) { bestv = m; bestj = j; }
    }
    float vwin; int jwin;
    block_argmax(bestv, bestj, pv, pj, buf, lane, w, vwin, jwin);
    q = cxyzb[jwin];
    if (t == 0) { fpsIdxb[r] = cidxb[jwin]; fpsXyzb[r] = q; }
    buf ^= 1;
  }
}

__global__ __launch_bounds__(FPS_T) void fps_kernel(
    const float* __restrict__ pc, const float4* __restrict__ cxyz,
    const int* __restrict__ cidx, const int* __restrict__ nv,
    int* __restrict__ fpsIdx, float4* __restrict__ fpsXyz,
    float* __restrict__ mindg) {
  __shared__ float pv[16];
  __shared__ int pj[16];
  int b = blockIdx.x;
  int nv_ = nv[b];
  const float4* cxyzb = cxyz + (size_t)b * NN;
  const int* cidxb = cidx + (size_t)b * NN;
  int* fpsIdxb = fpsIdx + (size_t)b * MM;
  float4* fpsXyzb = fpsXyz + (size_t)b * MM;
  if (nv_ == 0) {  // reference: argmax over all -inf = 0 every step
    int t = threadIdx.x;
    const float* pcb = pc + (size_t)b * NN * 3;
    float4 p0 = make_float4(pcb[0], pcb[1], pcb[2], 0.f);
    for (int r = t; r < MM; r += FPS_T) { fpsIdxb[r] = 0; fpsXyzb[r] = p0; }
    return;
  }
  int slots = (nv_ + FPS_T - 1) / FPS_T;
  if (slots <= 4)       fps_main<4>(nv_, cxyzb, cidxb, fpsIdxb, fpsXyzb, pv, pj);
  else if (slots <= 8)  fps_main<8>(nv_, cxyzb, cidxb, fpsIdxb, fpsXyzb, pv, pj);
  else if (slots <= 12) fps_main<12>(nv_, cxyzb, cidxb, fpsIdxb, fpsXyzb, pv, pj);
  else fps_fallback(nv_, cxyzb, cidxb, fpsIdxb, fpsXyzb,
                    mindg + (size_t)b * NN, pv, pj);
}

// ---------------------------------------------------------------------------
// Stage 3: three_nn (8 queries per 256-thread block) + weights
// ---------------------------------------------------------------------------
__device__ __forceinline__ bool nn_before(float ad, int ai, float bd, int bi) {
  return (ad < bd) || (ad == bd && ai < bi);  // stable ascending (top_k semantics)
}

__device__ __forceinline__ void merge3(float* ad, int* ai,
                                       float b0, float b1, float b2,
                                       int j0, int j1, int j2) {
  bool c0 = nn_before(ad[0], ai[0], b0, j0);
  float r0d = c0 ? ad[0] : b0; int r0i = c0 ? ai[0] : j0;
  float Xd = c0 ? b0 : ad[0];  int Xi = c0 ? j0 : ai[0];   // loser of rank-0
  bool c1 = nn_before(ad[1], ai[1], b1, j1);
  float Yd = c1 ? ad[1] : b1;  int Yi = c1 ? ai[1] : j1;   // min of rank-1s
  bool c2 = nn_before(Xd, Xi, Yd, Yi);
  float r1d = c2 ? Xd : Yd;    int r1i = c2 ? Xi : Yi;
  float Wd = c2 ? Yd : Xd;     int Wi = c2 ? Yi : Xi;
  bool c3 = nn_before(ad[2], ai[2], b2, j2);
  float Vd = c3 ? ad[2] : b2;  int Vi = c3 ? ai[2] : j2;   // min of rank-2s
  bool c4 = nn_before(Wd, Wi, Vd, Vi);
  float r2d = c4 ? Wd : Vd;    int r2i = c4 ? Wi : Vi;
  ad[0] = r0d; ad[1] = r1d; ad[2] = r2d;
  ai[0] = r0i; ai[1] = r1i; ai[2] = r2i;
}

__global__ void three_nn_kernel(const float* __restrict__ pc,
                                const float4* __restrict__ fpsXyz,
                                int* __restrict__ idx3,
                                float* __restrict__ w3) {
  const int blk = blockIdx.x;
  const int b = blk / (MM / QB);
  const int qbase = (blk % (MM / QB)) * QB;
  const int t = threadIdx.x;
  const int lane = t & 63, w = t >> 6;
  const float* pcb = pc + (size_t)b * NN * 3;
  float qx[QB], qy[QB], qz[QB];
#pragma unroll
  for (int qq = 0; qq < QB; ++qq) {
    float4 p = fpsXyz[(size_t)b * MM + qbase + qq];
    qx[qq] = p.x; qy[qq] = p.y; qz[qq] = p.z;
  }
  float qd[QB][3]; int qi[QB][3];
#pragma unroll
  for (int qq = 0; qq < QB; ++qq)
#pragma unroll
    for (int k = 0; k < 3; ++k) { qd[qq][k] = INFF; qi[qq][k] = 0x7fffffff; }

  const int nchunk = (NN + 255) / 256;
  for (int c = 0; c < nchunk; ++c) {
    int i = c * 256 + t;
    if (i < NN) {
      float px = pcb[3 * i], py = pcb[3 * i + 1], pz = pcb[3 * i + 2];
#pragma unroll
      for (int qq = 0; qq < QB; ++qq) {
        float dx = px - qx[qq], dy = py - qy[qq], dz = pz - qz[qq];
        float d = fmaf(dz, dz, fmaf(dy, dy, dx * dx));
        if (d < qd[qq][2]) {  // strict < keeps stable (earlier index first)
          bool lt0 = d < qd[qq][0], lt1 = d < qd[qq][1];
          qd[qq][2] = lt1 ? qd[qq][1] : d;  qi[qq][2] = lt1 ? qi[qq][1] : i;
          float nd1 = lt0 ? qd[qq][0] : (lt1 ? d : qd[qq][1]);
          int   ni1 = lt0 ? qi[qq][0] : (lt1 ? i : qi[qq][1]);
          qd[qq][1] = nd1; qi[qq][1] = ni1;
          qd[qq][0] = lt0 ? d : qd[qq][0];  qi[qq][0] = lt0 ? i : qi[qq][0];
        }
      }
    }
  }
  // wave butterfly merge of sorted triples
#pragma unroll
  for (int off = 32; off; off >>= 1) {
#pragma unroll
    for (int qq = 0; qq < QB; ++qq) {
      float bd0 = __shfl_xor(qd[qq][0], off);
      float bd1 = __shfl_xor(qd[qq][1], off);
      float bd2 = __shfl_xor(qd[qq][2], off);
      int bi0 = __shfl_xor(qi[qq][0], off);
      int bi1 = __shfl_xor(qi[qq][1], off);
      int bi2 = __shfl_xor(qi[qq][2], off);
      merge3(qd[qq], qi[qq], bd0, bd1, bd2, bi0, bi1, bi2);
    }
  }
  __shared__ float smd[4][QB][3];
  __shared__ int smi[4][QB][3];
  if (lane == 0) {
#pragma unroll
    for (int qq = 0; qq < QB; ++qq)
#pragma unroll
      for (int k = 0; k < 3; ++k) { smd[w][qq][k] = qd[qq][k]; smi[w][qq][k] = qi[qq][k]; }
  }
  __syncthreads();
  if (t < QB) {
    int qq = t;
    float fd[3]; int fi[3];
#pragma unroll
    for (int k = 0; k < 3; ++k) { fd[k] = smd[0][qq][k]; fi[k] = smi[0][qq][k]; }
#pragma unroll
    for (int ww = 1; ww < 4; ++ww)
      merge3(fd, fi, smd[ww][qq][0], smd[ww][qq][1], smd[ww][qq][2],
             smi[ww][qq][0], smi[ww][qq][1], smi[ww][qq][2]);
    float wa = 1.f / (sqrtf(fmaxf(fd[0], 0.f)) + 1e-8f);
    float wb = 1.f / (sqrtf(fmaxf(fd[1], 0.f)) + 1e-8f);
    float wc = 1.f / (sqrtf(fmaxf(fd[2], 0.f)) + 1e-8f);
    float s = wa + wb + wc;
    size_t base3 = ((size_t)b * MM + qbase + qq) * 3;
    w3[base3] = wa / s; w3[base3 + 1] = wb / s; w3[base3 + 2] = wc / s;
    idx3[base3] = fi[0]; idx3[base3 + 1] = fi[1]; idx3[base3 + 2] = fi[2];
  }
}

// ---------------------------------------------------------------------------
// Stage 4: three_interpolate (one block per (b,c) feature row)
// ---------------------------------------------------------------------------
__global__ void interp_kernel(const float* __restrict__ seed,
                              const int* __restrict__ idx3,
                              const float* __restrict__ w3,
                              float* __restrict__ out) {
  const int blk = blockIdx.x;
  const int b = blk / CC;
  const int c = blk % CC;
  const float* row = seed + ((size_t)b * CC + c) * NN;
  const int t = threadIdx.x;
#pragma unroll
  for (int u = 0; u < MM / 256; ++u) {
    int m = u * 256 + t;
    size_t base3 = ((size_t)b * MM + m) * 3;
    int i0 = idx3[base3], i1 = idx3[base3 + 1], i2 = idx3[base3 + 2];
    float w0 = w3[base3], w1 = w3[base3 + 1], w2 = w3[base3 + 2];
    float v = fmaf(w2, row[i2], fmaf(w1, row[i1], w0 * row[i0]));
    out[((size_t)b * CC + c) * MM + m] = v;
  }
}

// ---------------------------------------------------------------------------
extern "C" void kernel_launch(void* const* d_in, const int* in_sizes, int n_in,
                              void* d_out, int out_size, void* d_ws,
                              size_t ws_size, hipStream_t stream) {
  (void)in_sizes; (void)n_in; (void)out_size; (void)ws_size;
  const float* pc = (const float*)d_in[0];     // (B,N,3)
  const float* seed = (const float*)d_in[1];   // (B,C,N)
  const float* obj = (const float*)d_in[2];    // (B,2,N)
  const float* grasp = (const float*)d_in[3];  // (B,N)
  float* out = (float*)d_out;                  // (B,C,M)

  char* p = (char*)d_ws;
  float4* cxyz = (float4*)p;  p += sizeof(float4) * BB * NN;
  int* cidx = (int*)p;        p += sizeof(int) * BB * NN;
  int* nv = (int*)p;          p += sizeof(int) * BB;
  int* fpsIdx = (int*)p;      p += sizeof(int) * BB * MM;
  p = (char*)(((uintptr_t)p + 15) & ~(uintptr_t)15);
  float4* fpsXyz = (float4*)p; p += sizeof(float4) * BB * MM;
  int* idx3 = (int*)p;        p += sizeof(int) * BB * MM * 3;
  float* w3 = (float*)p;      p += sizeof(float) * BB * MM * 3;
  float* mindg = (float*)p;   p += sizeof(float) * BB * NN;

  hipLaunchKernelGGL(compact_kernel, dim3(BB), dim3(256), 0, stream,
                     pc, obj, grasp, cxyz, cidx, nv);
  hipLaunchKernelGGL(fps_kernel, dim3(BB), dim3(FPS_T), 0, stream,
                     pc, cxyz, cidx, nv, fpsIdx, fpsXyz, mindg);
  hipLaunchKernelGGL(three_nn_kernel, dim3(BB * MM / QB), dim3(256), 0, stream,
                     pc, fpsXyz, idx3, w3);
  hipLaunchKernelGGL(interp_kernel, dim3(BB * CC), dim3(256), 0, stream,
                     seed, idx3, w3, out);
}

// Round 3
// 1132.545 us; speedup vs baseline: 1.4345x; 1.4345x over previous
//
#include <hip/hip_runtime.h>
#include <cstdint>

#define BB 4
#define NN 20000
#define CC 512
#define MM 1024
#define GTHR 0.1f
#define FPS_T 512
#define LDSCAP 5120   // max compacted points held in LDS (3*4B*5120 = 60KB)
#define QB 8

#define INFF __builtin_huge_valf()

// ---------------------------------------------------------------------------
// Stage 1: mask + order-preserving compaction (one block per batch, 1024 thr)
// Wave w owns contiguous span [w*1250, (w+1)*1250) so global order preserved.
// ---------------------------------------------------------------------------
__global__ __launch_bounds__(1024) void compact_kernel(
    const float* __restrict__ pc, const float* __restrict__ obj,
    const float* __restrict__ grasp, float4* __restrict__ cxyz,
    int* __restrict__ nv) {
  const int b = blockIdx.x;
  const int t = threadIdx.x;
  const int lane = t & 63, w = t >> 6;
  __shared__ int wtot[16];
  const float* pcb = pc + (size_t)b * NN * 3;
  const float* o0 = obj + (size_t)b * 2 * NN;
  const float* o1 = o0 + NN;
  const float* gb = grasp + (size_t)b * NN;
  float4* cxyzb = cxyz + (size_t)b * NN;

  const int SPAN = 1250;  // 16 waves * 1250 = 20000 exactly
  const int wstart = w * SPAN;

  unsigned vmask = 0;  // 20 group-valid bits
  int cnt = 0;
#pragma unroll
  for (int g = 0; g < 20; ++g) {
    int off = g * 64 + lane;
    bool v = false;
    if (off < SPAN) {
      int i = wstart + off;
      float a0 = o0[i], a1 = o1[i], gg = gb[i];
      // argmax(axis=1)==1  <=>  o1 > o0 strictly (argmax picks first max)
      v = (a1 > a0) && (gg > GTHR);
    }
    unsigned long long bal = __ballot(v);
    if (v) vmask |= (1u << g);
    cnt += (int)__popcll(bal);
  }
  if (lane == 0) wtot[w] = cnt;
  __syncthreads();
  int base = 0;
#pragma unroll
  for (int k = 0; k < 16; ++k)
    if (k < w) base += wtot[k];
#pragma unroll
  for (int g = 0; g < 20; ++g) {
    int off = g * 64 + lane;
    bool v = (vmask >> g) & 1u;
    unsigned long long bal = __ballot(v);
    if (v) {
      int i = wstart + off;
      int pos = base + (int)__popcll(bal & ((1ull << lane) - 1ull));
      cxyzb[pos] = make_float4(pcb[3 * i], pcb[3 * i + 1], pcb[3 * i + 2], 0.f);
    }
    base += (int)__popcll(bal);
  }
  if (t == 0) {
    int tot = 0;
#pragma unroll
    for (int k = 0; k < 16; ++k) tot += wtot[k];
    nv[b] = tot;
  }
}

// ---------------------------------------------------------------------------
// Stage 2: FPS. Key idea: argmax reduction carries ONLY a packed u64 key
//   key = (float_bits(dist) << 32) | ~j
// (dist >= 0 so float bits are order-preserving; ~j makes ties pick the
// smallest j, matching jnp.argmax first-occurrence over the order-preserving
// compaction). Winner coordinates come from an LDS-resident copy of the
// compacted cloud via 3 broadcast ds_reads — nothing global, nothing carried.
// ---------------------------------------------------------------------------
template <int K>
__device__ void fps_lds(int nv_, const float4* __restrict__ cxyzb,
                        float4* __restrict__ fpsXyzb,
                        float* lx, float* ly, float* lz,
                        unsigned long long (*pk)[8]) {
  const int t = threadIdx.x;
  const int lane = t & 63, w = t >> 6;
  float x[K], y[K], z[K], mind[K];
#pragma unroll
  for (int s = 0; s < K; ++s) {
    int j = s * FPS_T + t;
    if (j < nv_) {
      float4 p = cxyzb[j];
      x[s] = p.x; y[s] = p.y; z[s] = p.z; mind[s] = INFF;
      lx[j] = p.x; ly[j] = p.y; lz[j] = p.z;
    } else {
      // invalid slot: mind pinned to 0 -> m stays 0; ties at 0 lose on index
      // because its fake j = s*FPS_T+t >= nv_ exceeds any real index.
      x[s] = 0.f; y[s] = 0.f; z[s] = 0.f; mind[s] = 0.f;
    }
  }
  __syncthreads();
  float qx = lx[0], qy = ly[0], qz = lz[0];  // first pick = first valid point
  if (t == 0) fpsXyzb[0] = make_float4(qx, qy, qz, 0.f);
  int buf = 0;
  for (int r = 1; r < MM; ++r) {
    float bm = -1.f;
    int bs = 0;
#pragma unroll
    for (int s = 0; s < K; ++s) {
      float dx = x[s] - qx, dy = y[s] - qy, dz = z[s] - qz;
      float d = fmaf(dz, dz, fmaf(dy, dy, dx * dx));
      float m = fminf(mind[s], d);
      mind[s] = m;
      bool better = m > bm;  // strict >: earliest slot (smallest j) wins ties
      bm = better ? m : bm;
      bs = better ? s : bs;
    }
    unsigned j = (unsigned)(bs * FPS_T + t);
    unsigned long long key =
        ((unsigned long long)__float_as_uint(bm) << 32) | (unsigned)(~j);
#pragma unroll
    for (int off = 32; off; off >>= 1) {
      unsigned long long ok = __shfl_xor(key, off);
      key = ok > key ? ok : key;
    }
    if (lane == 0) pk[buf][w] = key;
    __syncthreads();
    // cross-wave merge: lane reads entry (lane&7); 3-level 8-lane butterfly
    unsigned long long k0 = pk[buf][lane & 7];
    unsigned long long k1 = __shfl_xor(k0, 1); k0 = k1 > k0 ? k1 : k0;
    k1 = __shfl_xor(k0, 2); k0 = k1 > k0 ? k1 : k0;
    k1 = __shfl_xor(k0, 4); k0 = k1 > k0 ? k1 : k0;
    unsigned jw = ~(unsigned)(k0 & 0xffffffffull);  // global winner index
    qx = lx[jw]; qy = ly[jw]; qz = lz[jw];          // broadcast ds_reads
    if (t == 0) fpsXyzb[r] = make_float4(qx, qy, qz, 0.f);
    buf ^= 1;
  }
}

// slow-but-correct path for nv > LDSCAP (not expected with bench data)
__device__ void fps_fallback(int nv_, const float4* __restrict__ cxyzb,
                             float4* __restrict__ fpsXyzb,
                             float* __restrict__ mindg,
                             unsigned long long (*pk)[8]) {
  const int t = threadIdx.x;
  const int lane = t & 63, w = t >> 6;
  for (int j = t; j < nv_; j += FPS_T) mindg[j] = INFF;
  __syncthreads();
  float4 q = cxyzb[0];
  float qx = q.x, qy = q.y, qz = q.z;
  if (t == 0) fpsXyzb[0] = make_float4(qx, qy, qz, 0.f);
  int buf = 0;
  for (int r = 1; r < MM; ++r) {
    float bm = -1.f;
    int bj = 0x7fffffff;
    for (int j = t; j < nv_; j += FPS_T) {
      float4 p = cxyzb[j];
      float dx = p.x - qx, dy = p.y - qy, dz = p.z - qz;
      float d = fmaf(dz, dz, fmaf(dy, dy, dx * dx));
      float m = fminf(mindg[j], d);
      mindg[j] = m;
      bool better = m > bm;  // j ascending: strict > keeps smallest j
      bm = better ? m : bm;
      bj = better ? j : bj;
    }
    unsigned long long key =
        ((unsigned long long)__float_as_uint(bm) << 32) | (unsigned)(~bj);
#pragma unroll
    for (int off = 32; off; off >>= 1) {
      unsigned long long ok = __shfl_xor(key, off);
      key = ok > key ? ok : key;
    }
    if (lane == 0) pk[buf][w] = key;
    __syncthreads();
    unsigned long long k0 = pk[buf][lane & 7];
    unsigned long long k1 = __shfl_xor(k0, 1); k0 = k1 > k0 ? k1 : k0;
    k1 = __shfl_xor(k0, 2); k0 = k1 > k0 ? k1 : k0;
    k1 = __shfl_xor(k0, 4); k0 = k1 > k0 ? k1 : k0;
    unsigned jw = ~(unsigned)(k0 & 0xffffffffull);
    float4 qq = cxyzb[jw];
    qx = qq.x; qy = qq.y; qz = qq.z;
    if (t == 0) fpsXyzb[r] = make_float4(qx, qy, qz, 0.f);
    buf ^= 1;
  }
}

__global__ __launch_bounds__(FPS_T) void fps_kernel(
    const float* __restrict__ pc, const float4* __restrict__ cxyz,
    const int* __restrict__ nv, float4* __restrict__ fpsXyz,
    float* __restrict__ mindg) {
  __shared__ float lx[LDSCAP], ly[LDSCAP], lz[LDSCAP];
  __shared__ unsigned long long pk[2][8];
  int b = blockIdx.x;
  int nv_ = nv[b];
  const float4* cxyzb = cxyz + (size_t)b * NN;
  float4* fpsXyzb = fpsXyz + (size_t)b * MM;
  if (nv_ == 0) {  // reference: argmax over all -inf = index 0 every step
    int t = threadIdx.x;
    const float* pcb = pc + (size_t)b * NN * 3;
    float4 p0 = make_float4(pcb[0], pcb[1], pcb[2], 0.f);
    for (int r = t; r < MM; r += FPS_T) fpsXyzb[r] = p0;
    return;
  }
  int slots = (nv_ + FPS_T - 1) / FPS_T;
  if (slots <= 3)       fps_lds<3>(nv_, cxyzb, fpsXyzb, lx, ly, lz, pk);
  else if (slots <= 6)  fps_lds<6>(nv_, cxyzb, fpsXyzb, lx, ly, lz, pk);
  else if (slots <= 9)  fps_lds<9>(nv_, cxyzb, fpsXyzb, lx, ly, lz, pk);
  else if (slots <= 10) fps_lds<10>(nv_, cxyzb, fpsXyzb, lx, ly, lz, pk);
  else fps_fallback(nv_, cxyzb, fpsXyzb, mindg + (size_t)b * NN, pk);
}

// ---------------------------------------------------------------------------
// Stage 3: three_nn (8 queries per 256-thread block) + weights
// ---------------------------------------------------------------------------
__device__ __forceinline__ bool nn_before(float ad, int ai, float bd, int bi) {
  return (ad < bd) || (ad == bd && ai < bi);  // stable ascending (top_k)
}

__device__ __forceinline__ void merge3(float* ad, int* ai,
                                       float b0, float b1, float b2,
                                       int j0, int j1, int j2) {
  bool c0 = nn_before(ad[0], ai[0], b0, j0);
  float r0d = c0 ? ad[0] : b0; int r0i = c0 ? ai[0] : j0;
  float Xd = c0 ? b0 : ad[0];  int Xi = c0 ? j0 : ai[0];
  bool c1 = nn_before(ad[1], ai[1], b1, j1);
  float Yd = c1 ? ad[1] : b1;  int Yi = c1 ? ai[1] : j1;
  bool c2 = nn_before(Xd, Xi, Yd, Yi);
  float r1d = c2 ? Xd : Yd;    int r1i = c2 ? Xi : Yi;
  float Wd = c2 ? Yd : Xd;     int Wi = c2 ? Yi : Xi;
  bool c3 = nn_before(ad[2], ai[2], b2, j2);
  float Vd = c3 ? ad[2] : b2;  int Vi = c3 ? ai[2] : j2;
  bool c4 = nn_before(Wd, Wi, Vd, Vi);
  float r2d = c4 ? Wd : Vd;    int r2i = c4 ? Wi : Vi;
  ad[0] = r0d; ad[1] = r1d; ad[2] = r2d;
  ai[0] = r0i; ai[1] = r1i; ai[2] = r2i;
}

__global__ void three_nn_kernel(const float* __restrict__ pc,
                                const float4* __restrict__ fpsXyz,
                                int* __restrict__ idx3,
                                float* __restrict__ w3) {
  const int blk = blockIdx.x;
  const int b = blk / (MM / QB);
  const int qbase = (blk % (MM / QB)) * QB;
  const int t = threadIdx.x;
  const int lane = t & 63, w = t >> 6;
  const float* pcb = pc + (size_t)b * NN * 3;
  float qx[QB], qy[QB], qz[QB];
#pragma unroll
  for (int qq = 0; qq < QB; ++qq) {
    float4 p = fpsXyz[(size_t)b * MM + qbase + qq];
    qx[qq] = p.x; qy[qq] = p.y; qz[qq] = p.z;
  }
  float qd[QB][3]; int qi[QB][3];
#pragma unroll
  for (int qq = 0; qq < QB; ++qq)
#pragma unroll
    for (int k = 0; k < 3; ++k) { qd[qq][k] = INFF; qi[qq][k] = 0x7fffffff; }

  const int nchunk = (NN + 255) / 256;
  for (int c = 0; c < nchunk; ++c) {
    int i = c * 256 + t;
    if (i < NN) {
      float pxx = pcb[3 * i], pyy = pcb[3 * i + 1], pzz = pcb[3 * i + 2];
#pragma unroll
      for (int qq = 0; qq < QB; ++qq) {
        float dx = pxx - qx[qq], dy = pyy - qy[qq], dz = pzz - qz[qq];
        float d = fmaf(dz, dz, fmaf(dy, dy, dx * dx));
        if (d < qd[qq][2]) {
          bool lt0 = d < qd[qq][0], lt1 = d < qd[qq][1];
          qd[qq][2] = lt1 ? qd[qq][1] : d;  qi[qq][2] = lt1 ? qi[qq][1] : i;
          float nd1 = lt0 ? qd[qq][0] : (lt1 ? d : qd[qq][1]);
          int   ni1 = lt0 ? qi[qq][0] : (lt1 ? i : qi[qq][1]);
          qd[qq][1] = nd1; qi[qq][1] = ni1;
          qd[qq][0] = lt0 ? d : qd[qq][0];  qi[qq][0] = lt0 ? i : qi[qq][0];
        }
      }
    }
  }
#pragma unroll
  for (int off = 32; off; off >>= 1) {
#pragma unroll
    for (int qq = 0; qq < QB; ++qq) {
      float bd0 = __shfl_xor(qd[qq][0], off);
      float bd1 = __shfl_xor(qd[qq][1], off);
      float bd2 = __shfl_xor(qd[qq][2], off);
      int bi0 = __shfl_xor(qi[qq][0], off);
      int bi1 = __shfl_xor(qi[qq][1], off);
      int bi2 = __shfl_xor(qi[qq][2], off);
      merge3(qd[qq], qi[qq], bd0, bd1, bd2, bi0, bi1, bi2);
    }
  }
  __shared__ float smd[4][QB][3];
  __shared__ int smi[4][QB][3];
  if (lane == 0) {
#pragma unroll
    for (int qq = 0; qq < QB; ++qq)
#pragma unroll
      for (int k = 0; k < 3; ++k) { smd[w][qq][k] = qd[qq][k]; smi[w][qq][k] = qi[qq][k]; }
  }
  __syncthreads();
  if (t < QB) {
    int qq = t;
    float fd[3]; int fi[3];
#pragma unroll
    for (int k = 0; k < 3; ++k) { fd[k] = smd[0][qq][k]; fi[k] = smi[0][qq][k]; }
#pragma unroll
    for (int ww = 1; ww < 4; ++ww)
      merge3(fd, fi, smd[ww][qq][0], smd[ww][qq][1], smd[ww][qq][2],
             smi[ww][qq][0], smi[ww][qq][1], smi[ww][qq][2]);
    float wa = 1.f / (sqrtf(fmaxf(fd[0], 0.f)) + 1e-8f);
    float wb = 1.f / (sqrtf(fmaxf(fd[1], 0.f)) + 1e-8f);
    float wc = 1.f / (sqrtf(fmaxf(fd[2], 0.f)) + 1e-8f);
    float s = wa + wb + wc;
    size_t base3 = ((size_t)b * MM + qbase + qq) * 3;
    w3[base3] = wa / s; w3[base3 + 1] = wb / s; w3[base3 + 2] = wc / s;
    idx3[base3] = fi[0]; idx3[base3 + 1] = fi[1]; idx3[base3 + 2] = fi[2];
  }
}

// ---------------------------------------------------------------------------
// Stage 4: three_interpolate (one block per (b,c) feature row)
// ---------------------------------------------------------------------------
__global__ void interp_kernel(const float* __restrict__ seed,
                              const int* __restrict__ idx3,
                              const float* __restrict__ w3,
                              float* __restrict__ out) {
  const int blk = blockIdx.x;
  const int b = blk / CC;
  const int c = blk % CC;
  const float* row = seed + ((size_t)b * CC + c) * NN;
  const int t = threadIdx.x;
#pragma unroll
  for (int u = 0; u < MM / 256; ++u) {
    int m = u * 256 + t;
    size_t base3 = ((size_t)b * MM + m) * 3;
    int i0 = idx3[base3], i1 = idx3[base3 + 1], i2 = idx3[base3 + 2];
    float w0 = w3[base3], w1 = w3[base3 + 1], w2 = w3[base3 + 2];
    float v = fmaf(w2, row[i2], fmaf(w1, row[i1], w0 * row[i0]));
    out[((size_t)b * CC + c) * MM + m] = v;
  }
}

// ---------------------------------------------------------------------------
extern "C" void kernel_launch(void* const* d_in, const int* in_sizes, int n_in,
                              void* d_out, int out_size, void* d_ws,
                              size_t ws_size, hipStream_t stream) {
  (void)in_sizes; (void)n_in; (void)out_size; (void)ws_size;
  const float* pc = (const float*)d_in[0];     // (B,N,3)
  const float* seed = (const float*)d_in[1];   // (B,C,N)
  const float* obj = (const float*)d_in[2];    // (B,2,N)
  const float* grasp = (const float*)d_in[3];  // (B,N)
  float* out = (float*)d_out;                  // (B,C,M)

  char* p = (char*)d_ws;
  float4* cxyz = (float4*)p;   p += sizeof(float4) * BB * NN;
  float4* fpsXyz = (float4*)p; p += sizeof(float4) * BB * MM;
  int* idx3 = (int*)p;         p += sizeof(int) * BB * MM * 3;
  float* w3 = (float*)p;       p += sizeof(float) * BB * MM * 3;
  float* mindg = (float*)p;    p += sizeof(float) * BB * NN;
  int* nv = (int*)p;           p += sizeof(int) * BB;

  hipLaunchKernelGGL(compact_kernel, dim3(BB), dim3(1024), 0, stream,
                     pc, obj, grasp, cxyz, nv);
  hipLaunchKernelGGL(fps_kernel, dim3(BB), dim3(FPS_T), 0, stream,
                     pc, cxyz, nv, fpsXyz, mindg);
  hipLaunchKernelGGL(three_nn_kernel, dim3(BB * MM / QB), dim3(256), 0, stream,
                     pc, fpsXyz, idx3, w3);
  hipLaunchKernelGGL(interp_kernel, dim3(BB * CC), dim3(256), 0, stream,
                     seed, idx3, w3, out);
}